// Round 17
// baseline (478.780 us; speedup 1.0000x reference)
//
#include <hip/hip_runtime.h>
#include <math.h>

#define B_ 16
#define N_ 4096
#define D_ 64
#define K_ 8
#define H_ 4
#define HID_ 256
#define ITERS_ 3
#define EPS_ 1e-5f

// DH * (-0.5 * D * ln(2*pi)) = 16 * (-58.812066125099056)
#define HTERM_ (-940.9930580015849f)

__device__ __forceinline__ float waveReduceSum64(float v) {
  v += __shfl_xor(v, 1);  v += __shfl_xor(v, 2);  v += __shfl_xor(v, 4);
  v += __shfl_xor(v, 8);  v += __shfl_xor(v, 16); v += __shfl_xor(v, 32);
  return v;
}
__device__ __forceinline__ float groupReduceSum16(float v) {
  v += __shfl_xor(v, 1); v += __shfl_xor(v, 2); v += __shfl_xor(v, 4);
  v += __shfl_xor(v, 8);
  return v;
}

// DPP-based sum over each 16-lane row (result in all 16 lanes) — VALU pipe.
template <int CTRL>
__device__ __forceinline__ float dpp_mov(float v) {
  return __int_as_float(__builtin_amdgcn_update_dpp(
      0, __float_as_int(v), CTRL, 0xF, 0xF, true));
}
__device__ __forceinline__ float row16Sum(float v) {
  v += dpp_mov<0xB1>(v);   // quad_perm(1,0,3,2)  : lane ^ 1
  v += dpp_mov<0x4E>(v);   // quad_perm(2,3,0,1)  : lane ^ 2
  v += dpp_mov<0x124>(v);  // row_ror:4
  v += dpp_mov<0x128>(v);  // row_ror:8
  return v;
}

// ---- register-free global->LDS stage of one 512-float keys row ----
// HW contract (m104/m108): LDS dest = wave-uniform base + lane*size;
// global src is per-lane. lane i fetches row[i*16B] -> LDS linear copy.
__device__ __forceinline__ void stage_row(const float* rowg, float* ldsrow, int lane) {
#if __has_builtin(__builtin_amdgcn_global_load_lds)
  typedef __attribute__((address_space(1))) const float GF;
  typedef __attribute__((address_space(3))) float LF;
  __builtin_amdgcn_global_load_lds((GF*)(rowg + lane * 4),       (LF*)ldsrow,         16, 0, 0);
  __builtin_amdgcn_global_load_lds((GF*)(rowg + 256 + lane * 4), (LF*)(ldsrow + 256), 16, 0, 0);
#else
  #pragma unroll
  for (int j = 0; j < 4; ++j) {
    ldsrow[lane * 4 + j]       = rowg[lane * 4 + j];
    ldsrow[256 + lane * 4 + j] = rowg[256 + lane * 4 + j];
  }
#endif
}

// ---------- B: LN(emb) fused + keys einsum, ALL K per block ----------
// Writes x (LN output, side effect) and keys[bl][n][k][d].
__global__ __launch_bounds__(256) void key_kernel(const float* __restrict__ emb,
    const float* __restrict__ g_in, const float* __restrict__ b_in,
    const float* __restrict__ Wk, float* __restrict__ x,
    float* __restrict__ keys, int b0) {
  __shared__ float xst[64 * 68];    // xst[e][n] = LN(emb)[n0+n][e]
  __shared__ float wks[64 * 64];
  int n0 = blockIdx.x * 64;
  int bl = blockIdx.y;              // local b
  int tid = threadIdx.x;
  int wave = tid >> 6, lane = tid & 63;

  // ---- fused LayerNorm staging: each wave handles 16 rows ----
  {
    const float* eb = emb + ((size_t)(b0 + bl) * N_ + n0 + wave * 16) * 64 + lane;
    float* xrow = x + ((size_t)bl * N_ + n0 + wave * 16) * 64 + lane;
    float gl = g_in[lane], bb = b_in[lane];
    #pragma unroll 4
    for (int r = 0; r < 16; ++r) {
      float e = eb[(size_t)r * 64];
      float s  = waveReduceSum64(e);
      float sq = waveReduceSum64(e * e);
      float mean = s * (1.0f / 64.0f);
      float var  = sq * (1.0f / 64.0f) - mean * mean;
      float xv = (e - mean) * rsqrtf(var + EPS_) * gl + bb;
      xst[lane * 68 + wave * 16 + r] = xv;
      xrow[(size_t)r * 64] = xv;
    }
  }

  int tr = tid >> 4, tc = tid & 15;
  int r0 = tr * 4, c0 = tc * 4;
  size_t outb = ((size_t)bl * N_ + n0) * 512;

  for (int k = 0; k < K_; ++k) {
    __syncthreads();                // xst ready / prev pass done reading wks
    const float4* wk4 = (const float4*)(Wk + (size_t)k * 4096);
    float4* wks4 = (float4*)wks;
    for (int i = tid; i < 1024; i += 256) wks4[i] = wk4[i];
    __syncthreads();

    float ak[4][4] = {{0.f}};
    #pragma unroll 8
    for (int kk = 0; kk < 64; ++kk) {
      float4 xq = *(const float4*)&xst[kk * 68 + r0];
      float4 wq = *(const float4*)&wks[kk * 64 + c0];
      float xv[4] = {xq.x, xq.y, xq.z, xq.w};
      float wc[4] = {wq.x, wq.y, wq.z, wq.w};
      #pragma unroll
      for (int i = 0; i < 4; ++i)
        #pragma unroll
        for (int j = 0; j < 4; ++j)
          ak[i][j] = fmaf(xv[i], wc[j], ak[i][j]);
    }
    size_t ob = outb + (size_t)k * 64;
    #pragma unroll
    for (int i = 0; i < 4; ++i) {
      float4 kq = make_float4(ak[i][0], ak[i][1], ak[i][2], ak[i][3]);
      *(float4*)&keys[ob + (size_t)(r0 + i) * 512 + c0] = kq;
    }
  }
}

// ---------- init: slots, q, i2s, base for iter 0 + zero accumulators ----------
__global__ void init_kernel(const float* __restrict__ mu, const float* __restrict__ lsig,
                            const float* __restrict__ mix0, const float* __restrict__ noise,
                            const float* __restrict__ tq,
                            const float* __restrict__ g_sl, const float* __restrict__ b_sl,
                            float* __restrict__ slots, float* __restrict__ q,
                            float* __restrict__ i2s, float* __restrict__ base,
                            float* __restrict__ S1, float* __restrict__ S2,
                            float* __restrict__ S0, float* __restrict__ T, int b0) {
  int bk = b0 * K_ + blockIdx.x;               // global b*K index
  int lane = threadIdx.x;                      // 64 threads
  int k = bk & (K_ - 1);
  int kd = k * 64 + lane;
  float sg = expf(lsig[kd]);
  float s = mu[kd] + sg * noise[bk * 64 + lane];
  slots[bk * 64 + lane] = s;
  // LN(slots) -> q
  float su = waveReduceSum64(s);
  float sq = waveReduceSum64(s * s);
  float mean = su * (1.0f / 64.0f);
  float var  = sq * (1.0f / 64.0f) - mean * mean;
  float sl = (s - mean) * rsqrtf(var + EPS_) * g_sl[lane] + b_sl[lane];
  q[bk * 64 + lane] = sl * tq[k * 4096 + lane * 65];   // diagonal of to_queries
  i2s[bk * 64 + lane] = 0.5f / (sg * sg + EPS_);
  float ls = -logf(fmaxf(sg, EPS_));
  float lss = groupReduceSum16(ls);
  if ((lane & 15) == 0)
    base[bk * 4 + (lane >> 4)] = logf(mix0[k] + EPS_) + HTERM_ + lss;
  // zero this bk's accumulator slices (attn accumulates atomically)
  S1[bk * 64 + lane] = 0.0f;
  S2[bk * 64 + lane] = 0.0f;
  T[bk * 256 + lane]       = 0.0f;
  T[bk * 256 + 64 + lane]  = 0.0f;
  T[bk * 256 + 128 + lane] = 0.0f;
  T[bk * 256 + 192 + lane] = 0.0f;
  if (lane < 4) S0[bk * 4 + lane] = 0.0f;
}

// ---------- C: attention pass, MEASURED-BEST geometry + LDS key staging ----------
// 256 threads, 4 waves x 16 rows, 64 rows/block, VGPR=48 baseline (no-spill
// max: R6/R7/R9/R15 all spill when exceeded). This round: keys rows staged
// via global_load_lds into wave-private LDS double-buffers with counted
// vmcnt(2) — register-FREE latency hiding (the only path the spill wall
// leaves open). No barriers in the pipeline (wave-private buffers), so the
// vmcnt-drain-at-barrier problem doesn't apply. Do NOT fuse update tail
// (R13: per-block device fence -> 4x).
template <bool WRITE_ATTN>
__global__ __launch_bounds__(256, 4) void attn_kernel(
    const float* __restrict__ keys, const float* __restrict__ x,
    const float* __restrict__ q, const float* __restrict__ i2s, const float* __restrict__ base,
    float* __restrict__ S1, float* __restrict__ S2, float* __restrict__ S0,
    float* __restrict__ T, float* __restrict__ attn_out, int b0) {
  int bl = blockIdx.y;            // local b
  int bg = b0 + bl;               // global b
  int wave = threadIdx.x >> 6, lane = threadIdx.x & 63;
  int h = lane >> 4;
  int n0 = (blockIdx.x * 4 + wave) * 16;

  __shared__ float att_lds[4][K_][64];      // [wave][k][ni*4+h]
  __shared__ float blk[3104];               // S1 512 | S2 512 | T 2048 | S0 32
  __shared__ float bv_lds[32];              // base[bg, k, h]
  __shared__ __align__(16) float kbuf[4][2][512];  // wave-private key-row dbuf
  for (int i = threadIdx.x; i < 3104; i += 256) blk[i] = 0.0f;
  if (threadIdx.x < 32) bv_lds[threadIdx.x] = base[bg * 32 + threadIdx.x];

  // qv/iv: one base address, K_ imm-offset loads each
  float qv[K_], iv[K_];
  {
    const float* qp = q + bg * 512 + lane;
    const float* ip = i2s + bg * 512 + lane;
    #pragma unroll
    for (int k = 0; k < K_; ++k) { qv[k] = qp[k * 64]; iv[k] = ip[k * 64]; }
  }
  float s1a[K_] = {0.f}, s2a[K_] = {0.f};
  __syncthreads();

  // ---- phase 1: distances, softmax, key-moments; attn -> LDS ----
  // Pipeline: prologue stages rows 0,1; per iter: vmcnt(2) guarantees row ni
  // landed (oldest-retire-first; row ni+1's 2 instrs stay in flight), read it,
  // then stage row ni+2 into the freed buffer so DMA overlaps compute.
  const float* rowbase = keys + ((size_t)bl * N_ + n0) * 512;
  stage_row(rowbase,       &kbuf[wave][0][0], lane);
  stage_row(rowbase + 512, &kbuf[wave][1][0], lane);
  for (int ni = 0; ni < 16; ++ni) {
    if (ni < 15) { asm volatile("s_waitcnt vmcnt(2)" ::: "memory"); }
    else         { asm volatile("s_waitcnt vmcnt(0)" ::: "memory"); }
    __builtin_amdgcn_sched_barrier(0);
    float key[K_];
    const float* kb = &kbuf[wave][ni & 1][0];
    #pragma unroll
    for (int k = 0; k < K_; ++k) key[k] = kb[k * 64 + lane];  // 2-way banks: free
    if (ni < 14) {
      asm volatile("s_waitcnt lgkmcnt(0)" ::: "memory");  // reads done before DMA reuse
      __builtin_amdgcn_sched_barrier(0);
      stage_row(rowbase + (size_t)(ni + 2) * 512, &kbuf[wave][ni & 1][0], lane);
    }
    float gl[K_];
    #pragma unroll
    for (int k = 0; k < K_; ++k) {
      float df = key[k] - qv[k];
      float t = row16Sum(df * df * iv[k]);   // sum over 16 dims of this head
      gl[k] = bv_lds[k * 4 + h] - t;         // LDS broadcast read
    }
    float m = gl[0];
    #pragma unroll
    for (int k = 1; k < K_; ++k) m = fmaxf(m, gl[k]);
    float ssum = 0.f;
    #pragma unroll
    for (int k = 0; k < K_; ++k) { gl[k] = __expf(gl[k] - m); ssum += gl[k]; }
    float inv = __builtin_amdgcn_rcpf(ssum);
    #pragma unroll
    for (int k = 0; k < K_; ++k) {
      float a = gl[k] * inv + EPS_;          // attn (with +EPS, as in reference)
      s1a[k] = fmaf(a, key[k], s1a[k]);
      s2a[k] = fmaf(a * key[k], key[k], s2a[k]);
      if ((lane & 15) == 0) att_lds[wave][k][ni * 4 + h] = a;
    }
  }
  // flush key-moments to LDS now (frees 16 VGPRs for phase 2)
  #pragma unroll
  for (int k = 0; k < K_; ++k) {
    atomicAdd(&blk[k * 64 + lane],       s1a[k]);
    atomicAdd(&blk[512 + k * 64 + lane], s2a[k]);
  }

  // ---- phase 2: T[h][e] += sum_n a[n,h]*x[n][e]; S0 from att_lds ----
  float xr[16];
  {
    const float* xptr = x + ((size_t)bl * N_ + n0) * 64 + lane;
    #pragma unroll
    for (int ni = 0; ni < 16; ++ni) xr[ni] = xptr[ni * 64];  // imm offsets
  }
  #pragma unroll
  for (int k = 0; k < K_; ++k) {
    float t0 = 0.f, t1 = 0.f, t2 = 0.f, t3 = 0.f;
    float c0 = 0.f, c1 = 0.f, c2 = 0.f, c3 = 0.f;
    #pragma unroll
    for (int ni = 0; ni < 16; ++ni) {
      float4 a4 = *(const float4*)&att_lds[wave][k][ni * 4];  // broadcast read
      float xv = xr[ni];
      t0 = fmaf(a4.x, xv, t0); t1 = fmaf(a4.y, xv, t1);
      t2 = fmaf(a4.z, xv, t2); t3 = fmaf(a4.w, xv, t3);
      c0 += a4.x; c1 += a4.y; c2 += a4.z; c3 += a4.w;
    }
    atomicAdd(&blk[1024 + k * 256 + lane],       t0);
    atomicAdd(&blk[1024 + k * 256 + 64 + lane],  t1);
    atomicAdd(&blk[1024 + k * 256 + 128 + lane], t2);
    atomicAdd(&blk[1024 + k * 256 + 192 + lane], t3);
    if (lane == 0) {
      atomicAdd(&blk[3072 + k * 4 + 0], c0);
      atomicAdd(&blk[3072 + k * 4 + 1], c1);
      atomicAdd(&blk[3072 + k * 4 + 2], c2);
      atomicAdd(&blk[3072 + k * 4 + 3], c3);
    }
  }
  __syncthreads();
  // block -> global, one atomic per element (measured-free vs P-store path)
  for (int i = threadIdx.x; i < 512; i += 256) {
    atomicAdd(&S1[bg * 512 + i], blk[i]);
    atomicAdd(&S2[bg * 512 + i], blk[512 + i]);
  }
  for (int i = threadIdx.x; i < 2048; i += 256)
    atomicAdd(&T[bg * 2048 + i], blk[1024 + i]);
  if (threadIdx.x < 32) atomicAdd(&S0[bg * 32 + threadIdx.x], blk[3072 + threadIdx.x]);
  if (WRITE_ATTN) {
    #pragma unroll
    for (int k = 0; k < K_; ++k)
      attn_out[((size_t)(bg * K_ + k) * N_ + n0) * 4 + lane] = att_lds[wave][k][lane];
  }
}

// ---------- E: SINGLE-WAVE update. 64 threads, ZERO barriers. ----------
__global__ __launch_bounds__(64) void update_kernel(
    float* __restrict__ S1, float* __restrict__ S2,
    float* __restrict__ S0, float* __restrict__ T,
    const float* __restrict__ Wv,
    float* __restrict__ slots,
    const float* __restrict__ w_ih, const float* __restrict__ w_hh,
    const float* __restrict__ b_ih, const float* __restrict__ b_hh,
    const float* __restrict__ w1, const float* __restrict__ b1,
    const float* __restrict__ w2, const float* __restrict__ b2,
    const float* __restrict__ g_ff, const float* __restrict__ b_ff,
    const float* __restrict__ tq,
    const float* __restrict__ g_sl, const float* __restrict__ b_sl,
    float* __restrict__ q, float* __restrict__ i2s, float* __restrict__ base,
    const float* __restrict__ noise_final, float* __restrict__ out_slots,
    int last, int b0) {
  int bk = b0 * K_ + blockIdx.x;
  int k = bk & (K_ - 1);
  int t = threadIdx.x;                 // 0..63
  __shared__ float upd_s[64], sp_s[64], pre_s[64], hid_s[256];

  // ---- A: moments -> upd, sigma; stage upd/sp to LDS ----
  float nk = S0[bk * 4 + 0] + S0[bk * 4 + 1] + S0[bk * 4 + 2] + S0[bk * 4 + 3];
  float sv = 0.f;
  {
    const float* Trow = T + bk * 256 + (t >> 4) * 64;
    const float* wv = Wv + (size_t)k * 4096 + t;
    #pragma unroll 8
    for (int e = 0; e < 64; ++e) sv = fmaf(Trow[e], wv[(size_t)e * 64], sv);
  }
  float upd = (1.0f / nk + EPS_) * sv;
  upd_s[t] = upd;
  float s1 = S1[bk * 64 + t], s2 = S2[bk * 64 + t], s0 = S0[bk * 4 + (t >> 4)];
  float sig2 = fmaxf(s2 - 2.0f * upd * s1 + upd * upd * s0, 0.0f);
  float sig = sqrtf(sig2 / nk) + EPS_;
  float sp = slots[bk * 64 + t];
  sp_s[t] = sp;
  // accumulators consumed -> zero for next iteration's atomics
  S1[bk * 64 + t] = 0.0f;
  S2[bk * 64 + t] = 0.0f;
  T[bk * 256 + t]       = 0.0f;
  T[bk * 256 + 64 + t]  = 0.0f;
  T[bk * 256 + 128 + t] = 0.0f;
  T[bk * 256 + 192 + t] = 0.0f;
  if (t < 4) S0[bk * 4 + t] = 0.0f;

  // ---- B: GRU — each lane computes its d's three gates ----
  float xr_ = b_ih[t], xz_ = b_ih[64 + t], xn_ = b_ih[128 + t];
  float hr_ = b_hh[t], hz_ = b_hh[64 + t], hn_ = b_hh[128 + t];
  {
    const float4* wr = (const float4*)(w_ih + t * 64);
    const float4* wz = (const float4*)(w_ih + (64 + t) * 64);
    const float4* wn = (const float4*)(w_ih + (128 + t) * 64);
    const float4* vr = (const float4*)(w_hh + t * 64);
    const float4* vz = (const float4*)(w_hh + (64 + t) * 64);
    const float4* vn = (const float4*)(w_hh + (128 + t) * 64);
    #pragma unroll
    for (int d4 = 0; d4 < 16; ++d4) {
      float4 u4 = *(const float4*)&upd_s[d4 * 4];    // wave-local LDS, in-order
      float4 p4 = *(const float4*)&sp_s[d4 * 4];
      float4 a = wr[d4], b = wz[d4], c = wn[d4];
      float4 d = vr[d4], e = vz[d4], f = vn[d4];
      xr_ += u4.x * a.x + u4.y * a.y + u4.z * a.z + u4.w * a.w;
      xz_ += u4.x * b.x + u4.y * b.y + u4.z * b.z + u4.w * b.w;
      xn_ += u4.x * c.x + u4.y * c.y + u4.z * c.z + u4.w * c.w;
      hr_ += p4.x * d.x + p4.y * d.y + p4.z * d.z + p4.w * d.w;
      hz_ += p4.x * e.x + p4.y * e.y + p4.z * e.z + p4.w * e.w;
      hn_ += p4.x * f.x + p4.y * f.y + p4.z * f.z + p4.w * f.w;
    }
  }
  float r = 1.0f / (1.0f + expf(-(xr_ + hr_)));
  float z = 1.0f / (1.0f + expf(-(xz_ + hz_)));
  float nn = tanhf(xn_ + r * hn_);
  float sn = (1.0f - z) * nn + z * sp;

  // ---- C: LayerNorm(sn) -> pre (wave shuffle reduce) ----
  {
    float su = waveReduceSum64(sn);
    float sq = waveReduceSum64(sn * sn);
    float mean = su * (1.0f / 64.0f);
    float var  = sq * (1.0f / 64.0f) - mean * mean;
    pre_s[t] = (sn - mean) * rsqrtf(var + EPS_) * g_ff[t] + b_ff[t];
  }

  // ---- D: FFN layer 1 — each lane computes hid[4t..4t+3] ----
  {
    float a0 = b1[t * 4], a1 = b1[t * 4 + 1], a2 = b1[t * 4 + 2], a3 = b1[t * 4 + 3];
    const float4* w10 = (const float4*)(w1 + (t * 4) * 64);
    const float4* w11 = (const float4*)(w1 + (t * 4 + 1) * 64);
    const float4* w12 = (const float4*)(w1 + (t * 4 + 2) * 64);
    const float4* w13 = (const float4*)(w1 + (t * 4 + 3) * 64);
    #pragma unroll
    for (int d4 = 0; d4 < 16; ++d4) {
      float4 p4 = *(const float4*)&pre_s[d4 * 4];    // wave-local LDS
      float4 a = w10[d4], b = w11[d4], c = w12[d4], d = w13[d4];
      a0 += p4.x * a.x + p4.y * a.y + p4.z * a.z + p4.w * a.w;
      a1 += p4.x * b.x + p4.y * b.y + p4.z * b.z + p4.w * b.w;
      a2 += p4.x * c.x + p4.y * c.y + p4.z * c.z + p4.w * c.w;
      a3 += p4.x * d.x + p4.y * d.y + p4.z * d.z + p4.w * d.w;
    }
    *(float4*)&hid_s[t * 4] = make_float4(fmaxf(a0, 0.f), fmaxf(a1, 0.f),
                                          fmaxf(a2, 0.f), fmaxf(a3, 0.f));
  }

  // ---- E: FFN layer 2 + residual; outputs / next-iter prep ----
  {
    float a = b2[t];
    const float4* w2r = (const float4*)(w2 + t * 256);
    #pragma unroll
    for (int j4 = 0; j4 < 64; ++j4) {
      float4 w = w2r[j4];
      float4 hh = *(const float4*)&hid_s[j4 * 4];    // wave-local LDS broadcast
      a += hh.x * w.x + hh.y * w.y + hh.z * w.z + hh.w * w.w;
    }
    float outv = sn + a;
    slots[bk * 64 + t] = outv;
    if (last) {
      out_slots[bk * 64 + t] = outv + sig * noise_final[bk * 64 + t];
    } else {
      // ---- folded prep for next iteration ----
      float su = waveReduceSum64(outv);
      float sq = waveReduceSum64(outv * outv);
      float mean = su * (1.0f / 64.0f);
      float var  = sq * (1.0f / 64.0f) - mean * mean;
      float sl = (outv - mean) * rsqrtf(var + EPS_) * g_sl[t] + b_sl[t];
      q[bk * 64 + t] = sl * tq[k * 4096 + t * 65];   // diagonal of to_queries
      i2s[bk * 64 + t] = 0.5f / (sig * sig + EPS_);
      float ls = -logf(fmaxf(sig, EPS_));
      float lss = groupReduceSum16(ls);
      if ((t & 15) == 0)
        base[bk * 4 + (t >> 4)] = logf(nk * (1.0f / (float)N_) + EPS_) + HTERM_ + lss;
    }
  }
}

extern "C" void kernel_launch(void* const* d_in, const int* in_sizes, int n_in,
                              void* d_out, int out_size, void* d_ws, size_t ws_size,
                              hipStream_t stream) {
  const float* emb  = (const float*)d_in[0];
  const float* mu   = (const float*)d_in[1];
  const float* lsig = (const float*)d_in[2];
  const float* mix0 = (const float*)d_in[3];
  const float* Wk   = (const float*)d_in[4];
  const float* Wq   = (const float*)d_in[5];
  const float* Wv   = (const float*)d_in[6];
  const float* w_ih = (const float*)d_in[7];
  const float* w_hh = (const float*)d_in[8];
  const float* b_ih = (const float*)d_in[9];
  const float* b_hh = (const float*)d_in[10];
  const float* w1   = (const float*)d_in[11];
  const float* b1   = (const float*)d_in[12];
  const float* w2   = (const float*)d_in[13];
  const float* b2   = (const float*)d_in[14];
  const float* g_in = (const float*)d_in[15];
  const float* b_in = (const float*)d_in[16];
  const float* g_sl = (const float*)d_in[17];
  const float* b_sl = (const float*)d_in[18];
  const float* g_ff = (const float*)d_in[19];
  const float* b_ff = (const float*)d_in[20];
  const float* nz0  = (const float*)d_in[21];
  const float* nzf  = (const float*)d_in[22];

  float* ws = (float*)d_ws;
  float* slots = ws;                  // 8192  (full-B small buffers)
  float* q     = slots + 8192;        // 8192
  float* i2s   = q + 8192;            // 8192
  float* base  = i2s + 8192;          // 512
  float* S1    = base + 512;          // 8192
  float* S2    = S1 + 8192;           // 8192
  float* S0    = S2 + 8192;           // 512
  float* T     = S0 + 512;            // 32768
  float* x     = T + 32768;           // C*N*64   (per-chunk)
  const size_t small_bytes = (size_t)(5 * 8192 + 2 * 512 + 32768) * 4;
  // per-batch: x (N*64) + keys (N*512)
  const size_t per_batch = (size_t)(N_ * 64 + N_ * 512) * 4;

  int C = 16;
  while (C > 1 && small_bytes + (size_t)C * per_batch > ws_size) C >>= 1;
  float* keys = x + (size_t)C * N_ * 64;

  float* out_slots = (float*)d_out;
  float* out_attn  = out_slots + B_ * K_ * 64;

  for (int b0 = 0; b0 < B_; b0 += C) {
    key_kernel<<<dim3(N_ / 64, C), 256, 0, stream>>>(emb, g_in, b_in, Wk, x, keys, b0);
    init_kernel<<<dim3(C * K_), 64, 0, stream>>>(mu, lsig, mix0, nz0, Wq, g_sl, b_sl,
                                                 slots, q, i2s, base, S1, S2, S0, T, b0);
    for (int it = 0; it < ITERS_; ++it) {
      int last = (it == ITERS_ - 1) ? 1 : 0;
      if (last)
        attn_kernel<true><<<dim3(N_ / 64, C), 256, 0, stream>>>(keys, x, q, i2s, base,
                                                                S1, S2, S0, T, out_attn, b0);
      else
        attn_kernel<false><<<dim3(N_ / 64, C), 256, 0, stream>>>(keys, x, q, i2s, base,
                                                                 S1, S2, S0, T, nullptr, b0);
      update_kernel<<<dim3(C * K_), 64, 0, stream>>>(S1, S2, S0, T, Wv, slots,
          w_ih, w_hh, b_ih, b_hh, w1, b1, w2, b2, g_ff, b_ff,
          Wq, g_sl, b_sl, q, i2s, base, nzf, out_slots, last, b0);
    }
  }
}

// Round 18
// 469.304 us; speedup vs baseline: 1.0202x; 1.0202x over previous
//
#include <hip/hip_runtime.h>
#include <math.h>

#define B_ 16
#define N_ 4096
#define D_ 64
#define K_ 8
#define H_ 4
#define HID_ 256
#define ITERS_ 3
#define EPS_ 1e-5f

// DH * (-0.5 * D * ln(2*pi)) = 16 * (-58.812066125099056)
#define HTERM_ (-940.9930580015849f)

__device__ __forceinline__ float waveReduceSum64(float v) {
  v += __shfl_xor(v, 1);  v += __shfl_xor(v, 2);  v += __shfl_xor(v, 4);
  v += __shfl_xor(v, 8);  v += __shfl_xor(v, 16); v += __shfl_xor(v, 32);
  return v;
}
__device__ __forceinline__ float groupReduceSum16(float v) {
  v += __shfl_xor(v, 1); v += __shfl_xor(v, 2); v += __shfl_xor(v, 4);
  v += __shfl_xor(v, 8);
  return v;
}

// DPP-based sum over each 16-lane row (result in all 16 lanes) — VALU pipe.
template <int CTRL>
__device__ __forceinline__ float dpp_mov(float v) {
  return __int_as_float(__builtin_amdgcn_update_dpp(
      0, __float_as_int(v), CTRL, 0xF, 0xF, true));
}
__device__ __forceinline__ float row16Sum(float v) {
  v += dpp_mov<0xB1>(v);   // quad_perm(1,0,3,2)  : lane ^ 1
  v += dpp_mov<0x4E>(v);   // quad_perm(2,3,0,1)  : lane ^ 2
  v += dpp_mov<0x124>(v);  // row_ror:4
  v += dpp_mov<0x128>(v);  // row_ror:8
  return v;
}

// ---------- B: LN(emb) fused + keys einsum + FOLDED init (blockIdx.x==64) ----------
// Blocks [0,64): LN-stage 64 emb rows, write x, compute keys for all K.
// Block 64: per-batch init (slots, q, i2s, base, accumulator zeroing) —
// purely wave-local logic, 4 waves x 2 bk each. Deletes the init launch.
__global__ __launch_bounds__(256) void key_kernel(const float* __restrict__ emb,
    const float* __restrict__ g_in, const float* __restrict__ b_in,
    const float* __restrict__ Wk, float* __restrict__ x,
    float* __restrict__ keys,
    const float* __restrict__ mu, const float* __restrict__ lsig,
    const float* __restrict__ mix0, const float* __restrict__ noise,
    const float* __restrict__ tq,
    const float* __restrict__ g_sl, const float* __restrict__ b_sl,
    float* __restrict__ slots, float* __restrict__ q,
    float* __restrict__ i2s, float* __restrict__ base,
    float* __restrict__ S1, float* __restrict__ S2,
    float* __restrict__ S0, float* __restrict__ T, int b0) {
  int bl = blockIdx.y;              // local b
  int tid = threadIdx.x;
  int wave = tid >> 6, lane = tid & 63;

  if (blockIdx.x == 64) {
    // ---- folded init: this batch's 8 bk, 2 per wave ----
    #pragma unroll
    for (int u = 0; u < 2; ++u) {
      int k = wave * 2 + u;
      int bk = (b0 + bl) * K_ + k;
      int kd = k * 64 + lane;
      float sg = expf(lsig[kd]);
      float s = mu[kd] + sg * noise[bk * 64 + lane];
      slots[bk * 64 + lane] = s;
      float su = waveReduceSum64(s);
      float sq = waveReduceSum64(s * s);
      float mean = su * (1.0f / 64.0f);
      float var  = sq * (1.0f / 64.0f) - mean * mean;
      float sl = (s - mean) * rsqrtf(var + EPS_) * g_sl[lane] + b_sl[lane];
      q[bk * 64 + lane] = sl * tq[k * 4096 + lane * 65];   // diag of to_queries
      i2s[bk * 64 + lane] = 0.5f / (sg * sg + EPS_);
      float ls = -logf(fmaxf(sg, EPS_));
      float lss = groupReduceSum16(ls);
      if ((lane & 15) == 0)
        base[bk * 4 + (lane >> 4)] = logf(mix0[k] + EPS_) + HTERM_ + lss;
      S1[bk * 64 + lane] = 0.0f;
      S2[bk * 64 + lane] = 0.0f;
      T[bk * 256 + lane]       = 0.0f;
      T[bk * 256 + 64 + lane]  = 0.0f;
      T[bk * 256 + 128 + lane] = 0.0f;
      T[bk * 256 + 192 + lane] = 0.0f;
      if (lane < 4) S0[bk * 4 + lane] = 0.0f;
    }
    return;
  }

  __shared__ float xst[64 * 68];    // xst[e][n] = LN(emb)[n0+n][e]
  __shared__ float wks[64 * 64];
  int n0 = blockIdx.x * 64;

  // ---- fused LayerNorm staging: each wave handles 16 rows ----
  {
    const float* eb = emb + ((size_t)(b0 + bl) * N_ + n0 + wave * 16) * 64 + lane;
    float* xrow = x + ((size_t)bl * N_ + n0 + wave * 16) * 64 + lane;
    float gl = g_in[lane], bb = b_in[lane];
    #pragma unroll 4
    for (int r = 0; r < 16; ++r) {
      float e = eb[(size_t)r * 64];
      float s  = waveReduceSum64(e);
      float sq = waveReduceSum64(e * e);
      float mean = s * (1.0f / 64.0f);
      float var  = sq * (1.0f / 64.0f) - mean * mean;
      float xv = (e - mean) * rsqrtf(var + EPS_) * gl + bb;
      xst[lane * 68 + wave * 16 + r] = xv;
      xrow[(size_t)r * 64] = xv;
    }
  }

  int tr = tid >> 4, tc = tid & 15;
  int r0 = tr * 4, c0 = tc * 4;
  size_t outb = ((size_t)bl * N_ + n0) * 512;

  for (int k = 0; k < K_; ++k) {
    __syncthreads();                // xst ready / prev pass done reading wks
    const float4* wk4 = (const float4*)(Wk + (size_t)k * 4096);
    float4* wks4 = (float4*)wks;
    for (int i = tid; i < 1024; i += 256) wks4[i] = wk4[i];
    __syncthreads();

    float ak[4][4] = {{0.f}};
    #pragma unroll 8
    for (int kk = 0; kk < 64; ++kk) {
      float4 xq = *(const float4*)&xst[kk * 68 + r0];
      float4 wq = *(const float4*)&wks[kk * 64 + c0];
      float xv[4] = {xq.x, xq.y, xq.z, xq.w};
      float wc[4] = {wq.x, wq.y, wq.z, wq.w};
      #pragma unroll
      for (int i = 0; i < 4; ++i)
        #pragma unroll
        for (int j = 0; j < 4; ++j)
          ak[i][j] = fmaf(xv[i], wc[j], ak[i][j]);
    }
    size_t ob = outb + (size_t)k * 64;
    #pragma unroll
    for (int i = 0; i < 4; ++i) {
      float4 kq = make_float4(ak[i][0], ak[i][1], ak[i][2], ak[i][3]);
      *(float4*)&keys[ob + (size_t)(r0 + i) * 512 + c0] = kq;
    }
  }
}

// ---------- C: attention pass. MEASURED-BEST geometry (89.4-91.5us, double-
// measured): 256 threads, 4 waves x 16 rows, 64 rows/block, VGPR=48 no spill.
// Closed levers (all measured): min-waves>4 -> spill (R6/R7); rows/thread 32
// -> spill (R9); +8-reg prefetch -> spill (R15); global_load_lds DMA dbuf ->
// neutral (R17); occupancy is not the binding constraint (R8); atomic tail ==
// P-store tail (R10/R11); update fusion via per-block device fence -> 4x
// regression (R13). attn ~90us is the structural floor of this decomposition.
template <bool WRITE_ATTN>
__global__ __launch_bounds__(256, 4) void attn_kernel(
    const float* __restrict__ keys, const float* __restrict__ x,
    const float* __restrict__ q, const float* __restrict__ i2s, const float* __restrict__ base,
    float* __restrict__ S1, float* __restrict__ S2, float* __restrict__ S0,
    float* __restrict__ T, float* __restrict__ attn_out, int b0) {
  int bl = blockIdx.y;            // local b
  int bg = b0 + bl;               // global b
  int wave = threadIdx.x >> 6, lane = threadIdx.x & 63;
  int h = lane >> 4;
  int n0 = (blockIdx.x * 4 + wave) * 16;

  __shared__ float att_lds[4][K_][64];    // [wave][k][ni*4+h]
  __shared__ float blk[3104];             // S1 512 | S2 512 | T 2048 | S0 32
  __shared__ float bv_lds[32];            // base[bg, k, h]
  for (int i = threadIdx.x; i < 3104; i += 256) blk[i] = 0.0f;
  if (threadIdx.x < 32) bv_lds[threadIdx.x] = base[bg * 32 + threadIdx.x];

  // qv/iv: one base address, K_ imm-offset loads each
  float qv[K_], iv[K_];
  {
    const float* qp = q + bg * 512 + lane;
    const float* ip = i2s + bg * 512 + lane;
    #pragma unroll
    for (int k = 0; k < K_; ++k) { qv[k] = qp[k * 64]; iv[k] = ip[k * 64]; }
  }
  float s1a[K_] = {0.f}, s2a[K_] = {0.f};
  __syncthreads();

  // ---- phase 1: distances, softmax, key-moments; attn -> LDS ----
  const float* kptr = keys + ((size_t)bl * N_ + n0) * 512 + lane;
  #pragma unroll 2
  for (int ni = 0; ni < 16; ++ni) {
    float key[K_], gl[K_];
    #pragma unroll
    for (int k = 0; k < K_; ++k) key[k] = kptr[k * 64];   // imm offsets, one base
    #pragma unroll
    for (int k = 0; k < K_; ++k) {
      float df = key[k] - qv[k];
      float t = row16Sum(df * df * iv[k]);   // sum over 16 dims of this head
      gl[k] = bv_lds[k * 4 + h] - t;         // LDS broadcast read
    }
    float m = gl[0];
    #pragma unroll
    for (int k = 1; k < K_; ++k) m = fmaxf(m, gl[k]);
    float ssum = 0.f;
    #pragma unroll
    for (int k = 0; k < K_; ++k) { gl[k] = __expf(gl[k] - m); ssum += gl[k]; }
    float inv = __builtin_amdgcn_rcpf(ssum);
    #pragma unroll
    for (int k = 0; k < K_; ++k) {
      float a = gl[k] * inv + EPS_;          // attn (with +EPS, as in reference)
      s1a[k] = fmaf(a, key[k], s1a[k]);
      s2a[k] = fmaf(a * key[k], key[k], s2a[k]);
      if ((lane & 15) == 0) att_lds[wave][k][ni * 4 + h] = a;
    }
    kptr += 512;
  }
  // flush key-moments to LDS now (frees 16 VGPRs for phase 2)
  #pragma unroll
  for (int k = 0; k < K_; ++k) {
    atomicAdd(&blk[k * 64 + lane],       s1a[k]);
    atomicAdd(&blk[512 + k * 64 + lane], s2a[k]);
  }

  // ---- phase 2: T[h][e] += sum_n a[n,h]*x[n][e]; S0 from att_lds ----
  float xr[16];
  {
    const float* xptr = x + ((size_t)bl * N_ + n0) * 64 + lane;
    #pragma unroll
    for (int ni = 0; ni < 16; ++ni) xr[ni] = xptr[ni * 64];  // imm offsets
  }
  #pragma unroll
  for (int k = 0; k < K_; ++k) {
    float t0 = 0.f, t1 = 0.f, t2 = 0.f, t3 = 0.f;
    float c0 = 0.f, c1 = 0.f, c2 = 0.f, c3 = 0.f;
    #pragma unroll
    for (int ni = 0; ni < 16; ++ni) {
      float4 a4 = *(const float4*)&att_lds[wave][k][ni * 4];  // broadcast read
      float xv = xr[ni];
      t0 = fmaf(a4.x, xv, t0); t1 = fmaf(a4.y, xv, t1);
      t2 = fmaf(a4.z, xv, t2); t3 = fmaf(a4.w, xv, t3);
      c0 += a4.x; c1 += a4.y; c2 += a4.z; c3 += a4.w;
    }
    atomicAdd(&blk[1024 + k * 256 + lane],       t0);
    atomicAdd(&blk[1024 + k * 256 + 64 + lane],  t1);
    atomicAdd(&blk[1024 + k * 256 + 128 + lane], t2);
    atomicAdd(&blk[1024 + k * 256 + 192 + lane], t3);
    if (lane == 0) {
      atomicAdd(&blk[3072 + k * 4 + 0], c0);
      atomicAdd(&blk[3072 + k * 4 + 1], c1);
      atomicAdd(&blk[3072 + k * 4 + 2], c2);
      atomicAdd(&blk[3072 + k * 4 + 3], c3);
    }
  }
  __syncthreads();
  // block -> global, one atomic per element (measured-free vs P-store path)
  for (int i = threadIdx.x; i < 512; i += 256) {
    atomicAdd(&S1[bg * 512 + i], blk[i]);
    atomicAdd(&S2[bg * 512 + i], blk[512 + i]);
  }
  for (int i = threadIdx.x; i < 2048; i += 256)
    atomicAdd(&T[bg * 2048 + i], blk[1024 + i]);
  if (threadIdx.x < 32) atomicAdd(&S0[bg * 32 + threadIdx.x], blk[3072 + threadIdx.x]);
  if (WRITE_ATTN) {
    #pragma unroll
    for (int k = 0; k < K_; ++k)
      attn_out[((size_t)(bg * K_ + k) * N_ + n0) * 4 + lane] = att_lds[wave][k][lane];
  }
}

// ---------- E: SINGLE-WAVE update. 64 threads, ZERO barriers. ----------
__global__ __launch_bounds__(64) void update_kernel(
    float* __restrict__ S1, float* __restrict__ S2,
    float* __restrict__ S0, float* __restrict__ T,
    const float* __restrict__ Wv,
    float* __restrict__ slots,
    const float* __restrict__ w_ih, const float* __restrict__ w_hh,
    const float* __restrict__ b_ih, const float* __restrict__ b_hh,
    const float* __restrict__ w1, const float* __restrict__ b1,
    const float* __restrict__ w2, const float* __restrict__ b2,
    const float* __restrict__ g_ff, const float* __restrict__ b_ff,
    const float* __restrict__ tq,
    const float* __restrict__ g_sl, const float* __restrict__ b_sl,
    float* __restrict__ q, float* __restrict__ i2s, float* __restrict__ base,
    const float* __restrict__ noise_final, float* __restrict__ out_slots,
    int last, int b0) {
  int bk = b0 * K_ + blockIdx.x;
  int k = bk & (K_ - 1);
  int t = threadIdx.x;                 // 0..63
  __shared__ float upd_s[64], sp_s[64], pre_s[64], hid_s[256];

  // ---- A: moments -> upd, sigma; stage upd/sp to LDS ----
  float nk = S0[bk * 4 + 0] + S0[bk * 4 + 1] + S0[bk * 4 + 2] + S0[bk * 4 + 3];
  float sv = 0.f;
  {
    const float* Trow = T + bk * 256 + (t >> 4) * 64;
    const float* wv = Wv + (size_t)k * 4096 + t;
    #pragma unroll 8
    for (int e = 0; e < 64; ++e) sv = fmaf(Trow[e], wv[(size_t)e * 64], sv);
  }
  float upd = (1.0f / nk + EPS_) * sv;
  upd_s[t] = upd;
  float s1 = S1[bk * 64 + t], s2 = S2[bk * 64 + t], s0 = S0[bk * 4 + (t >> 4)];
  float sig2 = fmaxf(s2 - 2.0f * upd * s1 + upd * upd * s0, 0.0f);
  float sig = sqrtf(sig2 / nk) + EPS_;
  float sp = slots[bk * 64 + t];
  sp_s[t] = sp;
  // accumulators consumed -> zero for next iteration's atomics
  S1[bk * 64 + t] = 0.0f;
  S2[bk * 64 + t] = 0.0f;
  T[bk * 256 + t]       = 0.0f;
  T[bk * 256 + 64 + t]  = 0.0f;
  T[bk * 256 + 128 + t] = 0.0f;
  T[bk * 256 + 192 + t] = 0.0f;
  if (t < 4) S0[bk * 4 + t] = 0.0f;

  // ---- B: GRU — each lane computes its d's three gates ----
  float xr_ = b_ih[t], xz_ = b_ih[64 + t], xn_ = b_ih[128 + t];
  float hr_ = b_hh[t], hz_ = b_hh[64 + t], hn_ = b_hh[128 + t];
  {
    const float4* wr = (const float4*)(w_ih + t * 64);
    const float4* wz = (const float4*)(w_ih + (64 + t) * 64);
    const float4* wn = (const float4*)(w_ih + (128 + t) * 64);
    const float4* vr = (const float4*)(w_hh + t * 64);
    const float4* vz = (const float4*)(w_hh + (64 + t) * 64);
    const float4* vn = (const float4*)(w_hh + (128 + t) * 64);
    #pragma unroll
    for (int d4 = 0; d4 < 16; ++d4) {
      float4 u4 = *(const float4*)&upd_s[d4 * 4];    // wave-local LDS, in-order
      float4 p4 = *(const float4*)&sp_s[d4 * 4];
      float4 a = wr[d4], b = wz[d4], c = wn[d4];
      float4 d = vr[d4], e = vz[d4], f = vn[d4];
      xr_ += u4.x * a.x + u4.y * a.y + u4.z * a.z + u4.w * a.w;
      xz_ += u4.x * b.x + u4.y * b.y + u4.z * b.z + u4.w * b.w;
      xn_ += u4.x * c.x + u4.y * c.y + u4.z * c.z + u4.w * c.w;
      hr_ += p4.x * d.x + p4.y * d.y + p4.z * d.z + p4.w * d.w;
      hz_ += p4.x * e.x + p4.y * e.y + p4.z * e.z + p4.w * e.w;
      hn_ += p4.x * f.x + p4.y * f.y + p4.z * f.z + p4.w * f.w;
    }
  }
  float r = 1.0f / (1.0f + expf(-(xr_ + hr_)));
  float z = 1.0f / (1.0f + expf(-(xz_ + hz_)));
  float nn = tanhf(xn_ + r * hn_);
  float sn = (1.0f - z) * nn + z * sp;

  // ---- C: LayerNorm(sn) -> pre (wave shuffle reduce) ----
  {
    float su = waveReduceSum64(sn);
    float sq = waveReduceSum64(sn * sn);
    float mean = su * (1.0f / 64.0f);
    float var  = sq * (1.0f / 64.0f) - mean * mean;
    pre_s[t] = (sn - mean) * rsqrtf(var + EPS_) * g_ff[t] + b_ff[t];
  }

  // ---- D: FFN layer 1 — each lane computes hid[4t..4t+3] ----
  {
    float a0 = b1[t * 4], a1 = b1[t * 4 + 1], a2 = b1[t * 4 + 2], a3 = b1[t * 4 + 3];
    const float4* w10 = (const float4*)(w1 + (t * 4) * 64);
    const float4* w11 = (const float4*)(w1 + (t * 4 + 1) * 64);
    const float4* w12 = (const float4*)(w1 + (t * 4 + 2) * 64);
    const float4* w13 = (const float4*)(w1 + (t * 4 + 3) * 64);
    #pragma unroll
    for (int d4 = 0; d4 < 16; ++d4) {
      float4 p4 = *(const float4*)&pre_s[d4 * 4];    // wave-local LDS
      float4 a = w10[d4], b = w11[d4], c = w12[d4], d = w13[d4];
      a0 += p4.x * a.x + p4.y * a.y + p4.z * a.z + p4.w * a.w;
      a1 += p4.x * b.x + p4.y * b.y + p4.z * b.z + p4.w * b.w;
      a2 += p4.x * c.x + p4.y * c.y + p4.z * c.z + p4.w * c.w;
      a3 += p4.x * d.x + p4.y * d.y + p4.z * d.z + p4.w * d.w;
    }
    *(float4*)&hid_s[t * 4] = make_float4(fmaxf(a0, 0.f), fmaxf(a1, 0.f),
                                          fmaxf(a2, 0.f), fmaxf(a3, 0.f));
  }

  // ---- E: FFN layer 2 + residual; outputs / next-iter prep ----
  {
    float a = b2[t];
    const float4* w2r = (const float4*)(w2 + t * 256);
    #pragma unroll
    for (int j4 = 0; j4 < 64; ++j4) {
      float4 w = w2r[j4];
      float4 hh = *(const float4*)&hid_s[j4 * 4];    // wave-local LDS broadcast
      a += hh.x * w.x + hh.y * w.y + hh.z * w.z + hh.w * w.w;
    }
    float outv = sn + a;
    slots[bk * 64 + t] = outv;
    if (last) {
      out_slots[bk * 64 + t] = outv + sig * noise_final[bk * 64 + t];
    } else {
      // ---- folded prep for next iteration ----
      float su = waveReduceSum64(outv);
      float sq = waveReduceSum64(outv * outv);
      float mean = su * (1.0f / 64.0f);
      float var  = sq * (1.0f / 64.0f) - mean * mean;
      float sl = (outv - mean) * rsqrtf(var + EPS_) * g_sl[t] + b_sl[t];
      q[bk * 64 + t] = sl * tq[k * 4096 + t * 65];   // diagonal of to_queries
      i2s[bk * 64 + t] = 0.5f / (sig * sig + EPS_);
      float ls = -logf(fmaxf(sig, EPS_));
      float lss = groupReduceSum16(ls);
      if ((t & 15) == 0)
        base[bk * 4 + (t >> 4)] = logf(nk * (1.0f / (float)N_) + EPS_) + HTERM_ + lss;
    }
  }
}

extern "C" void kernel_launch(void* const* d_in, const int* in_sizes, int n_in,
                              void* d_out, int out_size, void* d_ws, size_t ws_size,
                              hipStream_t stream) {
  const float* emb  = (const float*)d_in[0];
  const float* mu   = (const float*)d_in[1];
  const float* lsig = (const float*)d_in[2];
  const float* mix0 = (const float*)d_in[3];
  const float* Wk   = (const float*)d_in[4];
  const float* Wq   = (const float*)d_in[5];
  const float* Wv   = (const float*)d_in[6];
  const float* w_ih = (const float*)d_in[7];
  const float* w_hh = (const float*)d_in[8];
  const float* b_ih = (const float*)d_in[9];
  const float* b_hh = (const float*)d_in[10];
  const float* w1   = (const float*)d_in[11];
  const float* b1   = (const float*)d_in[12];
  const float* w2   = (const float*)d_in[13];
  const float* b2   = (const float*)d_in[14];
  const float* g_in = (const float*)d_in[15];
  const float* b_in = (const float*)d_in[16];
  const float* g_sl = (const float*)d_in[17];
  const float* b_sl = (const float*)d_in[18];
  const float* g_ff = (const float*)d_in[19];
  const float* b_ff = (const float*)d_in[20];
  const float* nz0  = (const float*)d_in[21];
  const float* nzf  = (const float*)d_in[22];

  float* ws = (float*)d_ws;
  float* slots = ws;                  // 8192  (full-B small buffers)
  float* q     = slots + 8192;        // 8192
  float* i2s   = q + 8192;            // 8192
  float* base  = i2s + 8192;          // 512
  float* S1    = base + 512;          // 8192
  float* S2    = S1 + 8192;           // 8192
  float* S0    = S2 + 8192;           // 512
  float* T     = S0 + 512;            // 32768
  float* x     = T + 32768;           // C*N*64   (per-chunk)
  const size_t small_bytes = (size_t)(5 * 8192 + 2 * 512 + 32768) * 4;
  // per-batch: x (N*64) + keys (N*512)
  const size_t per_batch = (size_t)(N_ * 64 + N_ * 512) * 4;

  int C = 16;
  while (C > 1 && small_bytes + (size_t)C * per_batch > ws_size) C >>= 1;
  float* keys = x + (size_t)C * N_ * 64;

  float* out_slots = (float*)d_out;
  float* out_attn  = out_slots + B_ * K_ * 64;

  for (int b0 = 0; b0 < B_; b0 += C) {
    // grid.x = 65: columns [0,64) compute keys, column 64 does the folded init
    key_kernel<<<dim3(N_ / 64 + 1, C), 256, 0, stream>>>(emb, g_in, b_in, Wk, x, keys,
        mu, lsig, mix0, nz0, Wq, g_sl, b_sl, slots, q, i2s, base, S1, S2, S0, T, b0);
    for (int it = 0; it < ITERS_; ++it) {
      int last = (it == ITERS_ - 1) ? 1 : 0;
      if (last)
        attn_kernel<true><<<dim3(N_ / 64, C), 256, 0, stream>>>(keys, x, q, i2s, base,
                                                                S1, S2, S0, T, out_attn, b0);
      else
        attn_kernel<false><<<dim3(N_ / 64, C), 256, 0, stream>>>(keys, x, q, i2s, base,
                                                                 S1, S2, S0, T, nullptr, b0);
      update_kernel<<<dim3(C * K_), 64, 0, stream>>>(S1, S2, S0, T, Wv, slots,
          w_ih, w_hh, b_ih, b_hh, w1, b1, w2, b2, g_ff, b_ff,
          Wq, g_sl, b_sl, q, i2s, base, nzf, out_slots, last, b0);
    }
  }
}